// Round 13
// baseline (187.466 us; speedup 1.0000x reference)
//
#include <hip/hip_runtime.h>
#include <cmath>

// Problem constants (match reference)
constexpr int Bc = 256;
constexpr int Lc = 512;
constexpr int Tc = 5;
constexpr int Dc = 300;    // 75 float4 per row; rows are 16B-aligned (1200 B)
constexpr int Cc = 3;
constexpr int Vc = 50000;
constexpr int TGT_P = 304; // padded target-vector pitch (floats, 16B-aligned)

// Target-vector table layout (12 rows of TGT_P floats in ws):
//  0: w_mem            1: w_vec          2: p2 = lin_w @ w_vec
//  3-5: Q0 cols (out_w) 6-8: Q1 = lin_w@Q0 cols   9-11: Q2 = lin_w@Q1 cols
// etab[v][12] = emb[v] . tgt[j]  (packed, 48 B/row)

__device__ __forceinline__ float wave_dot300(const float* __restrict__ x,
                                             const float* __restrict__ y,
                                             int lane) {
  const float4* x4 = (const float4*)x;
  const float4* y4 = (const float4*)y;
  float4 a = x4[lane], b = y4[lane];
  float p = a.x*b.x + a.y*b.y + a.z*b.z + a.w*b.w;
  if (lane < 11) {
    float4 c = x4[64 + lane], d = y4[64 + lane];
    p += c.x*d.x + c.y*d.y + c.z*d.z + c.w*d.w;
  }
#pragma unroll
  for (int off = 32; off; off >>= 1) p += __shfl_down(p, off, 64);
  return p;  // valid on lane 0
}

// ---------------------------------------------------------------------------
// prep1: p2 (blocks 0-74), Q1 (75-299), copies (300), vec0 (301-556)
// ---------------------------------------------------------------------------
__global__ __launch_bounds__(256) void prep1_kernel(
    const float* __restrict__ lin_w, const float* __restrict__ attn_w,
    const float* __restrict__ out_w, const int* __restrict__ tx,
    const int* __restrict__ tlen, const float* __restrict__ emb,
    float* __restrict__ tgt, float* __restrict__ vec0)
{
  const int blk = blockIdx.x, tid = threadIdx.x;
  const int wave = tid >> 6, lane = tid & 63;
  if (blk < 75) {                       // p2[k] = lin_w row k . w_vec
    const int k = blk * 4 + wave;
    float p = wave_dot300(lin_w + (size_t)k * Dc, attn_w + Dc, lane);
    if (lane == 0) tgt[2 * TGT_P + k] = p;
  } else if (blk < 300) {               // Q1[k][c] = lin_w row k . out_w col c
    const int idx = (blk - 75) * 4 + wave;   // 0..899
    const int k = idx / 3, c = idx - 3 * (idx / 3);
    const float4* x4 = (const float4*)(lin_w + (size_t)k * Dc);
    float4 a = x4[lane];
    const int d0 = 4 * lane;
    float p = a.x*out_w[(d0+0)*Cc+c] + a.y*out_w[(d0+1)*Cc+c]
            + a.z*out_w[(d0+2)*Cc+c] + a.w*out_w[(d0+3)*Cc+c];
    if (lane < 11) {
      float4 bb = x4[64 + lane];
      const int d1 = 256 + 4 * lane;
      p += bb.x*out_w[(d1+0)*Cc+c] + bb.y*out_w[(d1+1)*Cc+c]
         + bb.z*out_w[(d1+2)*Cc+c] + bb.w*out_w[(d1+3)*Cc+c];
    }
#pragma unroll
    for (int off = 32; off; off >>= 1) p += __shfl_down(p, off, 64);
    if (lane == 0) tgt[(6 + c) * TGT_P + k] = p;
  } else if (blk == 300) {              // copies + out_w transpose
    for (int i = tid; i < Dc; i += 256) {
      tgt[0 * TGT_P + i] = attn_w[i];
      tgt[1 * TGT_P + i] = attn_w[Dc + i];
      tgt[3 * TGT_P + i] = out_w[i * Cc + 0];
      tgt[4 * TGT_P + i] = out_w[i * Cc + 1];
      tgt[5 * TGT_P + i] = out_w[i * Cc + 2];
    }
  } else {                              // vec0 = v_aspect, b = blk-301
    const int b = blk - 301;
    const int tl = tlen[b];
    for (int d = tid; d < Dc; d += 256) {
      float s = 0.f;
#pragma unroll
      for (int t = 0; t < Tc; ++t)
        if (t < tl) s += emb[(size_t)tx[b * Tc + t] * Dc + d];
      vec0[b * Dc + d] = s / (float)tl;
    }
  }
}

// ---------------------------------------------------------------------------
// prep2: Q2[k][c] = lin_w row k . Q1 col c   (grid 225 x 256)
// ---------------------------------------------------------------------------
__global__ __launch_bounds__(256) void prep2_kernel(
    const float* __restrict__ lin_w, float* __restrict__ tgt)
{
  const int idx = blockIdx.x * 4 + (threadIdx.x >> 6);  // 0..899
  const int lane = threadIdx.x & 63;
  const int k = idx / 3, c = idx - 3 * (idx / 3);
  float p = wave_dot300(lin_w + (size_t)k * Dc, tgt + (6 + c) * TGT_P, lane);
  if (lane == 0) tgt[(9 + c) * TGT_P + k] = p;
}

// ---------------------------------------------------------------------------
// etab v4: QUARTER-WAVE rows. 16-lane group g handles row 4*gwid+g; lane q
// holds chunks q, q+16, q+32, q+48 (+64 if q<11). All three previous variants
// (52 µs each) shared the 64-lane 6-step reduce = 72 shfl/row; this cuts
// shuffles to 12/row (4-step xor-butterfly shared by 4 rows) and shortens the
// serial chain. Weights read per-(j,k) from L1 (R12: VGPR=40 proved these are
// free). One row-quad per wave: 3125 blocks, no loop, pure TLP.
// ---------------------------------------------------------------------------
__global__ __launch_bounds__(256) void etab_kernel(
    const float* __restrict__ emb, const float* __restrict__ tgt,
    float* __restrict__ etab)
{
  const int tid = threadIdx.x;
  const int gwid = blockIdx.x * 4 + (tid >> 6);   // 0..12499
  const int lane = tid & 63;
  const int q = lane & 15;        // chunk-lane within group
  const int g = lane >> 4;        // group = row within quad
  const int v = gwid * 4 + g;     // vocab row (< 50000 exactly)

  const float4* r4 = (const float4*)(emb + (size_t)v * Dc);
  float4 e0 = r4[q];
  float4 e1 = r4[q + 16];
  float4 e2 = r4[q + 32];
  float4 e3 = r4[q + 48];
  float4 e4 = (q < 11) ? r4[q + 64] : float4{0.f, 0.f, 0.f, 0.f};

  const float4* tgt4 = (const float4*)tgt;   // 76 float4 per target row
  float acc[12];
#pragma unroll
  for (int j = 0; j < 12; ++j) {
    const float4* w = tgt4 + j * 76;
    float4 w0 = w[q], w1 = w[q + 16], w2 = w[q + 32], w3 = w[q + 48];
    float4 w4 = (q < 11) ? w[q + 64] : float4{0.f, 0.f, 0.f, 0.f};
    float p = e0.x*w0.x + e0.y*w0.y + e0.z*w0.z + e0.w*w0.w;
    p += e1.x*w1.x + e1.y*w1.y + e1.z*w1.z + e1.w*w1.w;
    p += e2.x*w2.x + e2.y*w2.y + e2.z*w2.z + e2.w*w2.w;
    p += e3.x*w3.x + e3.y*w3.y + e3.z*w3.z + e3.w*w3.w;
    p += e4.x*w4.x + e4.y*w4.y + e4.z*w4.z + e4.w*w4.w;
    acc[j] = p;
  }
  // 4-step xor-butterfly within each 16-lane group; 12 chains interleaved
#pragma unroll
  for (int off = 8; off; off >>= 1) {
#pragma unroll
    for (int j = 0; j < 12; ++j) acc[j] += __shfl_xor(acc[j], off, 16);
  }
  if (q == 0) {
    float4* ot = (float4*)(etab + (size_t)v * 12);
    ot[0] = float4{acc[0], acc[1], acc[2],  acc[3]};
    ot[1] = float4{acc[4], acc[5], acc[6],  acc[7]};
    ot[2] = float4{acc[8], acc[9], acc[10], acc[11]};
  }
}

// ---------------------------------------------------------------------------
// hops: per-b scalar 3-hop chain. grid 256 x 512 (thread = l).
// ---------------------------------------------------------------------------
template <int N>
__device__ __forceinline__ void breduceN(float (&v)[N], float (*sred)[8],
                                         float* outRB, int wave, int lane,
                                         int tid) {
#pragma unroll
  for (int j = 0; j < N; ++j) {
    float a = v[j];
#pragma unroll
    for (int off = 32; off; off >>= 1) a += __shfl_down(a, off, 64);
    if (lane == 0) sred[wave][j] = a;
  }
  __syncthreads();
  if (tid == 0) {
#pragma unroll
    for (int j = 0; j < N; ++j) {
      float s = 0.f;
      for (int w = 0; w < 8; ++w) s += sred[w][j];
      outRB[j] = s;
    }
  }
  __syncthreads();
}

__device__ __forceinline__ float lds_dot300(const float* x,
                                            const float* __restrict__ y,
                                            int lane) {
  float p = 0.f;
  for (int i = lane; i < Dc; i += 64) p += x[i] * y[i];
#pragma unroll
  for (int off = 32; off; off >>= 1) p += __shfl_down(p, off, 64);
  return p;
}

__global__ __launch_bounds__(512) void hops_kernel(
    const int* __restrict__ cx, const int* __restrict__ clen,
    const int* __restrict__ tloc,
    const float* __restrict__ etab, const float* __restrict__ tgt,
    const float* __restrict__ vec0, const float* __restrict__ lin_w,
    const float* __restrict__ lin_b, const float* __restrict__ attn_b,
    const float* __restrict__ out_b, float* __restrict__ out)
{
  __shared__ float vec0S[Dc];
  __shared__ float lv0S[Dc];
  __shared__ float sred[8][8];
  __shared__ float CB[12];   // 0:a1 1:a2 2:cb1 3:cb2 4-6:cbl+ob 7:a3 8-10:qv
  __shared__ float RB[12];   // 0:A0f1 1:A0f2 2-4:A0g2 5:A1f1 6-8:A1g1 9-11:A2g0
  __shared__ float XB[2];

  const int b = blockIdx.x, tid = threadIdx.x;
  const int wave = tid >> 6, lane = tid & 63;
  const int cl = clen[b], loc = tloc[b];
  const float inv_cl = 1.0f / (float)cl;

  if (tid < Dc) vec0S[tid] = vec0[b * Dc + tid];

  // per-l scalars from etab (held in registers across all 3 hops)
  const int cxv = cx[b * Lc + tid];
  const float4* et = (const float4*)(etab + (size_t)cxv * 12);
  const float4 t0 = et[0], t1 = et[1], t2 = et[2];
  const float vl = 1.0f - fabsf((float)(tid - loc)) * inv_cl;
  const float m_l  = t0.x * vl, f1 = t0.y * vl, f2 = t0.z * vl;
  const float g0c0 = t0.w * vl, g0c1 = t1.x * vl, g0c2 = t1.y * vl;
  const float g1c0 = t1.z * vl, g1c1 = t1.w * vl, g1c2 = t2.x * vl;
  const float g2c0 = t2.y * vl, g2c1 = t2.z * vl, g2c2 = t2.w * vl;
  __syncthreads();

  // lv0 = vec0 @ lin_w (threads 0..299); const dots on waves 5-7
  if (tid < Dc) {
    float lv = 0.f;
    const float* __restrict__ lw = lin_w + tid;
#pragma unroll 4
    for (int k = 0; k < Dc; ++k) lv += vec0S[k] * lw[k * Dc];
    lv0S[tid] = lv;
  } else if (wave == 5) {
    float p = lds_dot300(vec0S, tgt + 1 * TGT_P, lane);   // a1
    if (lane == 0) CB[0] = p;
    p = lds_dot300(vec0S, tgt + 2 * TGT_P, lane);         // a2
    if (lane == 0) CB[1] = p;
  } else if (wave == 6) {
    float p = lds_dot300(lin_b, tgt + 1 * TGT_P, lane);   // cb1
    if (lane == 0) CB[2] = p;
    p = lds_dot300(lin_b, tgt + 2 * TGT_P, lane);         // cb2
    if (lane == 0) CB[3] = p;
  } else if (wave == 7) {
#pragma unroll
    for (int c = 0; c < 3; ++c) {
      float p = 0.f;
      for (int i = lane; i < Dc; i += 64)
        p += lin_b[i] * (tgt[(3+c)*TGT_P + i] + tgt[(6+c)*TGT_P + i] +
                         tgt[(9+c)*TGT_P + i]);
#pragma unroll
      for (int off = 32; off; off >>= 1) p += __shfl_down(p, off, 64);
      if (lane == 0) CB[4 + c] = p + out_b[c];            // cbl_c + ob_c
    }
  }
  __syncthreads();
  if (wave == 5) {
    float p = lds_dot300(lv0S, tgt + 2 * TGT_P, lane);    // a3 = lv0.p2
    if (lane == 0) CB[7] = p;
    p = lds_dot300(lv0S, tgt + 11 * TGT_P, lane);         // qv2
    if (lane == 0) CB[10] = p;
  } else if (wave == 6) {
    float p = lds_dot300(lv0S, tgt + 9 * TGT_P, lane);    // qv0
    if (lane == 0) CB[8] = p;
  } else if (wave == 7) {
    float p = lds_dot300(lv0S, tgt + 10 * TGT_P, lane);   // qv1
    if (lane == 0) CB[9] = p;
  }
  __syncthreads();

  const float ab = attn_b[0];
  float sdot = CB[0] + ab;

#pragma unroll
  for (int h = 0; h < 3; ++h) {
    float s = (tid < cl) ? tanhf(m_l + sdot) : -1e9f;
    float mx = s;
#pragma unroll
    for (int off = 32; off; off >>= 1) mx = fmaxf(mx, __shfl_down(mx, off, 64));
    if (lane == 0) sred[wave][0] = mx;
    __syncthreads();
    if (tid == 0) {
      float mm = sred[0][0];
      for (int w = 1; w < 8; ++w) mm = fmaxf(mm, sred[w][0]);
      XB[0] = mm;
    }
    __syncthreads();
    float e = expf(s - XB[0]);                 // masked rows -> exactly 0
    float sm = e;
#pragma unroll
    for (int off = 32; off; off >>= 1) sm += __shfl_down(sm, off, 64);
    if (lane == 0) sred[wave][0] = sm;
    __syncthreads();
    if (tid == 0) {
      float ss = 0.f;
      for (int w = 0; w < 8; ++w) ss += sred[w][0];
      XB[1] = 1.0f / ss;
    }
    __syncthreads();
    const float alpha = e * XB[1];

    if (h == 0) {
      float v[5] = {alpha*f1, alpha*f2, alpha*g2c0, alpha*g2c1, alpha*g2c2};
      breduceN<5>(v, sred, RB + 0, wave, lane, tid);
      sdot = RB[0] + CB[1] + CB[2] + ab;
    } else if (h == 1) {
      float v[4] = {alpha*f1, alpha*g1c0, alpha*g1c1, alpha*g1c2};
      breduceN<4>(v, sred, RB + 5, wave, lane, tid);
      sdot = RB[5] + RB[1] + CB[7] + CB[3] + CB[2] + ab;
    } else {
      float v[3] = {alpha*g0c0, alpha*g0c1, alpha*g0c2};
      breduceN<3>(v, sred, RB + 9, wave, lane, tid);
    }
  }

  if (tid < Cc)
    out[b * Cc + tid] = RB[9 + tid] + RB[6 + tid] + RB[2 + tid] +
                        CB[8 + tid] + CB[4 + tid];
}

extern "C" void kernel_launch(void* const* d_in, const int* in_sizes, int n_in,
                              void* d_out, int out_size, void* d_ws, size_t ws_size,
                              hipStream_t stream) {
  const int*   cx     = (const int*)  d_in[0];
  const int*   clen   = (const int*)  d_in[1];
  const int*   tx     = (const int*)  d_in[2];
  const int*   tlen   = (const int*)  d_in[3];
  const int*   tloc   = (const int*)  d_in[4];
  const float* emb    = (const float*)d_in[5];
  const float* attn_w = (const float*)d_in[6];
  const float* attn_b = (const float*)d_in[7];
  const float* lin_w  = (const float*)d_in[8];
  const float* lin_b  = (const float*)d_in[9];
  const float* out_w  = (const float*)d_in[10];
  const float* out_b  = (const float*)d_in[11];
  float* out = (float*)d_out;

  // ws layout (floats): tgt[12][304] | vec0[256*300] | etab[50000*12]  ~2.7 MB
  float* tgt   = (float*)d_ws;
  float* vec0  = tgt  + 12 * TGT_P;
  float* etab  = vec0 + Bc * Dc;

  prep1_kernel<<<557, 256, 0, stream>>>(lin_w, attn_w, out_w, tx, tlen, emb,
                                        tgt, vec0);
  prep2_kernel<<<225, 256, 0, stream>>>(lin_w, tgt);
  etab_kernel<<<3125, 256, 0, stream>>>(emb, tgt, etab);
  hops_kernel<<<Bc, 512, 0, stream>>>(cx, clen, tloc, etab, tgt, vec0,
                                      lin_w, lin_b, attn_b, out_b, out);
}

// Round 14
// 172.434 us; speedup vs baseline: 1.0872x; 1.0872x over previous
//
#include <hip/hip_runtime.h>
#include <cmath>

// Problem constants (match reference)
constexpr int Bc = 256;
constexpr int Lc = 512;
constexpr int Tc = 5;
constexpr int Dc = 300;    // 75 float4 per row; rows are 16B-aligned (1200 B)
constexpr int Cc = 3;
constexpr int Vc = 50000;
constexpr int TGT_P = 304; // padded target-vector pitch (floats, 16B-aligned)

// Target-vector table layout (12 rows of TGT_P floats in ws):
//  0: w_mem            1: w_vec          2: p2 = lin_w @ w_vec
//  3-5: Q0 cols (out_w) 6-8: Q1 = lin_w@Q0 cols   9-11: Q2 = lin_w@Q1 cols
// etab[v][12] = emb[v] . tgt[j]  (packed, 48 B/row)

__device__ __forceinline__ float wave_dot300(const float* __restrict__ x,
                                             const float* __restrict__ y,
                                             int lane) {
  const float4* x4 = (const float4*)x;
  const float4* y4 = (const float4*)y;
  float4 a = x4[lane], b = y4[lane];
  float p = a.x*b.x + a.y*b.y + a.z*b.z + a.w*b.w;
  if (lane < 11) {
    float4 c = x4[64 + lane], d = y4[64 + lane];
    p += c.x*d.x + c.y*d.y + c.z*d.z + c.w*d.w;
  }
#pragma unroll
  for (int off = 32; off; off >>= 1) p += __shfl_down(p, off, 64);
  return p;  // valid on lane 0
}

// ---------------------------------------------------------------------------
// prep1: p2 (blocks 0-74), Q1 (75-299), copies (300), vec0 (301-556)
// ---------------------------------------------------------------------------
__global__ __launch_bounds__(256) void prep1_kernel(
    const float* __restrict__ lin_w, const float* __restrict__ attn_w,
    const float* __restrict__ out_w, const int* __restrict__ tx,
    const int* __restrict__ tlen, const float* __restrict__ emb,
    float* __restrict__ tgt, float* __restrict__ vec0)
{
  const int blk = blockIdx.x, tid = threadIdx.x;
  const int wave = tid >> 6, lane = tid & 63;
  if (blk < 75) {                       // p2[k] = lin_w row k . w_vec
    const int k = blk * 4 + wave;
    float p = wave_dot300(lin_w + (size_t)k * Dc, attn_w + Dc, lane);
    if (lane == 0) tgt[2 * TGT_P + k] = p;
  } else if (blk < 300) {               // Q1[k][c] = lin_w row k . out_w col c
    const int idx = (blk - 75) * 4 + wave;   // 0..899
    const int k = idx / 3, c = idx - 3 * (idx / 3);
    const float4* x4 = (const float4*)(lin_w + (size_t)k * Dc);
    float4 a = x4[lane];
    const int d0 = 4 * lane;
    float p = a.x*out_w[(d0+0)*Cc+c] + a.y*out_w[(d0+1)*Cc+c]
            + a.z*out_w[(d0+2)*Cc+c] + a.w*out_w[(d0+3)*Cc+c];
    if (lane < 11) {
      float4 bb = x4[64 + lane];
      const int d1 = 256 + 4 * lane;
      p += bb.x*out_w[(d1+0)*Cc+c] + bb.y*out_w[(d1+1)*Cc+c]
         + bb.z*out_w[(d1+2)*Cc+c] + bb.w*out_w[(d1+3)*Cc+c];
    }
#pragma unroll
    for (int off = 32; off; off >>= 1) p += __shfl_down(p, off, 64);
    if (lane == 0) tgt[(6 + c) * TGT_P + k] = p;
  } else if (blk == 300) {              // copies + out_w transpose
    for (int i = tid; i < Dc; i += 256) {
      tgt[0 * TGT_P + i] = attn_w[i];
      tgt[1 * TGT_P + i] = attn_w[Dc + i];
      tgt[3 * TGT_P + i] = out_w[i * Cc + 0];
      tgt[4 * TGT_P + i] = out_w[i * Cc + 1];
      tgt[5 * TGT_P + i] = out_w[i * Cc + 2];
    }
  } else {                              // vec0 = v_aspect, b = blk-301
    const int b = blk - 301;
    const int tl = tlen[b];
    for (int d = tid; d < Dc; d += 256) {
      float s = 0.f;
#pragma unroll
      for (int t = 0; t < Tc; ++t)
        if (t < tl) s += emb[(size_t)tx[b * Tc + t] * Dc + d];
      vec0[b * Dc + d] = s / (float)tl;
    }
  }
}

// ---------------------------------------------------------------------------
// prep2: Q2[k][c] = lin_w row k . Q1 col c   (grid 225 x 256)
// ---------------------------------------------------------------------------
__global__ __launch_bounds__(256) void prep2_kernel(
    const float* __restrict__ lin_w, float* __restrict__ tgt)
{
  const int idx = blockIdx.x * 4 + (threadIdx.x >> 6);  // 0..899
  const int lane = threadIdx.x & 63;
  const int k = idx / 3, c = idx - 3 * (idx / 3);
  float p = wave_dot300(lin_w + (size_t)k * Dc, tgt + (6 + c) * TGT_P, lane);
  if (lane == 0) tgt[(9 + c) * TGT_P + k] = p;
}

// ---------------------------------------------------------------------------
// etab v5: R13's 16-lane-group math + SOFTWARE PIPELINE. R6/R11/R12/R13 all
// hit ~52 µs regardless of LDS/shuffles/occupancy/VGPR — the shared flaw was
// zero outstanding VMEM during each row's compute phase (~600 GB/s = 1-2 KB
// in flight, Little's law). Fix: register double-buffer — issue next quad's
// 5 float4 loads BEFORE computing current quad. Named regs (no dyn-indexed
// arrays: scratch risk). Grid 1024x256: 4096 waves, stride 16384, ~3 iters.
// ---------------------------------------------------------------------------
constexpr int ETAB_STRIDE = 16384;   // 4096 waves * 4 rows

__global__ __launch_bounds__(256) void etab_kernel(
    const float* __restrict__ emb, const float* __restrict__ tgt,
    float* __restrict__ etab)
{
  const int tid = threadIdx.x;
  const int gw = blockIdx.x * 4 + (tid >> 6);     // 0..4095
  const int lane = tid & 63;
  const int q = lane & 15;        // chunk-lane within group
  const int g = lane >> 4;        // group = row within quad
  const float4* tgt4 = (const float4*)tgt;        // 76 float4 per target row

  int v = gw * 4 + g;             // first row (< 16384, always valid)
  const float4* r4 = (const float4*)(emb + (size_t)v * Dc);
  float4 c0 = r4[q];
  float4 c1 = r4[q + 16];
  float4 c2 = r4[q + 32];
  float4 c3 = r4[q + 48];
  float4 c4 = (q < 11) ? r4[q + 64] : float4{0.f, 0.f, 0.f, 0.f};

  for (;;) {
    // ---- prefetch next quad (wave-uniform predicate: 848 = 4*212 exactly)
    const int vn = v + ETAB_STRIDE;
    const bool has_next = vn < Vc;
    float4 n0, n1, n2, n3, n4;
    if (has_next) {
      const float4* p4 = (const float4*)(emb + (size_t)vn * Dc);
      n0 = p4[q];
      n1 = p4[q + 16];
      n2 = p4[q + 32];
      n3 = p4[q + 48];
      n4 = (q < 11) ? p4[q + 64] : float4{0.f, 0.f, 0.f, 0.f};
    }
    // ---- compute current quad (weights stream from L1 — proven free)
    float acc[12];
#pragma unroll
    for (int j = 0; j < 12; ++j) {
      const float4* w = tgt4 + j * 76;
      float4 w0 = w[q], w1 = w[q + 16], w2 = w[q + 32], w3 = w[q + 48];
      float4 w4 = (q < 11) ? w[q + 64] : float4{0.f, 0.f, 0.f, 0.f};
      float p = c0.x*w0.x + c0.y*w0.y + c0.z*w0.z + c0.w*w0.w;
      p += c1.x*w1.x + c1.y*w1.y + c1.z*w1.z + c1.w*w1.w;
      p += c2.x*w2.x + c2.y*w2.y + c2.z*w2.z + c2.w*w2.w;
      p += c3.x*w3.x + c3.y*w3.y + c3.z*w3.z + c3.w*w3.w;
      p += c4.x*w4.x + c4.y*w4.y + c4.z*w4.z + c4.w*w4.w;
      acc[j] = p;
    }
    // 4-step xor-butterfly within each 16-lane group; 12 chains interleaved
#pragma unroll
    for (int off = 8; off; off >>= 1) {
#pragma unroll
      for (int j = 0; j < 12; ++j) acc[j] += __shfl_xor(acc[j], off, 16);
    }
    if (q == 0) {
      float4* ot = (float4*)(etab + (size_t)v * 12);
      ot[0] = float4{acc[0], acc[1], acc[2],  acc[3]};
      ot[1] = float4{acc[4], acc[5], acc[6],  acc[7]};
      ot[2] = float4{acc[8], acc[9], acc[10], acc[11]};
    }
    if (!has_next) break;
    v = vn;
    c0 = n0; c1 = n1; c2 = n2; c3 = n3; c4 = n4;
  }
}

// ---------------------------------------------------------------------------
// hops: per-b scalar 3-hop chain. grid 256 x 512 (thread = l).
// ---------------------------------------------------------------------------
template <int N>
__device__ __forceinline__ void breduceN(float (&v)[N], float (*sred)[8],
                                         float* outRB, int wave, int lane,
                                         int tid) {
#pragma unroll
  for (int j = 0; j < N; ++j) {
    float a = v[j];
#pragma unroll
    for (int off = 32; off; off >>= 1) a += __shfl_down(a, off, 64);
    if (lane == 0) sred[wave][j] = a;
  }
  __syncthreads();
  if (tid == 0) {
#pragma unroll
    for (int j = 0; j < N; ++j) {
      float s = 0.f;
      for (int w = 0; w < 8; ++w) s += sred[w][j];
      outRB[j] = s;
    }
  }
  __syncthreads();
}

__device__ __forceinline__ float lds_dot300(const float* x,
                                            const float* __restrict__ y,
                                            int lane) {
  float p = 0.f;
  for (int i = lane; i < Dc; i += 64) p += x[i] * y[i];
#pragma unroll
  for (int off = 32; off; off >>= 1) p += __shfl_down(p, off, 64);
  return p;
}

__global__ __launch_bounds__(512) void hops_kernel(
    const int* __restrict__ cx, const int* __restrict__ clen,
    const int* __restrict__ tloc,
    const float* __restrict__ etab, const float* __restrict__ tgt,
    const float* __restrict__ vec0, const float* __restrict__ lin_w,
    const float* __restrict__ lin_b, const float* __restrict__ attn_b,
    const float* __restrict__ out_b, float* __restrict__ out)
{
  __shared__ float vec0S[Dc];
  __shared__ float lv0S[Dc];
  __shared__ float sred[8][8];
  __shared__ float CB[12];   // 0:a1 1:a2 2:cb1 3:cb2 4-6:cbl+ob 7:a3 8-10:qv
  __shared__ float RB[12];   // 0:A0f1 1:A0f2 2-4:A0g2 5:A1f1 6-8:A1g1 9-11:A2g0
  __shared__ float XB[2];

  const int b = blockIdx.x, tid = threadIdx.x;
  const int wave = tid >> 6, lane = tid & 63;
  const int cl = clen[b], loc = tloc[b];
  const float inv_cl = 1.0f / (float)cl;

  if (tid < Dc) vec0S[tid] = vec0[b * Dc + tid];

  // per-l scalars from etab (held in registers across all 3 hops)
  const int cxv = cx[b * Lc + tid];
  const float4* et = (const float4*)(etab + (size_t)cxv * 12);
  const float4 t0 = et[0], t1 = et[1], t2 = et[2];
  const float vl = 1.0f - fabsf((float)(tid - loc)) * inv_cl;
  const float m_l  = t0.x * vl, f1 = t0.y * vl, f2 = t0.z * vl;
  const float g0c0 = t0.w * vl, g0c1 = t1.x * vl, g0c2 = t1.y * vl;
  const float g1c0 = t1.z * vl, g1c1 = t1.w * vl, g1c2 = t2.x * vl;
  const float g2c0 = t2.y * vl, g2c1 = t2.z * vl, g2c2 = t2.w * vl;
  __syncthreads();

  // lv0 = vec0 @ lin_w (threads 0..299); const dots on waves 5-7
  if (tid < Dc) {
    float lv = 0.f;
    const float* __restrict__ lw = lin_w + tid;
#pragma unroll 4
    for (int k = 0; k < Dc; ++k) lv += vec0S[k] * lw[k * Dc];
    lv0S[tid] = lv;
  } else if (wave == 5) {
    float p = lds_dot300(vec0S, tgt + 1 * TGT_P, lane);   // a1
    if (lane == 0) CB[0] = p;
    p = lds_dot300(vec0S, tgt + 2 * TGT_P, lane);         // a2
    if (lane == 0) CB[1] = p;
  } else if (wave == 6) {
    float p = lds_dot300(lin_b, tgt + 1 * TGT_P, lane);   // cb1
    if (lane == 0) CB[2] = p;
    p = lds_dot300(lin_b, tgt + 2 * TGT_P, lane);         // cb2
    if (lane == 0) CB[3] = p;
  } else if (wave == 7) {
#pragma unroll
    for (int c = 0; c < 3; ++c) {
      float p = 0.f;
      for (int i = lane; i < Dc; i += 64)
        p += lin_b[i] * (tgt[(3+c)*TGT_P + i] + tgt[(6+c)*TGT_P + i] +
                         tgt[(9+c)*TGT_P + i]);
#pragma unroll
      for (int off = 32; off; off >>= 1) p += __shfl_down(p, off, 64);
      if (lane == 0) CB[4 + c] = p + out_b[c];            // cbl_c + ob_c
    }
  }
  __syncthreads();
  if (wave == 5) {
    float p = lds_dot300(lv0S, tgt + 2 * TGT_P, lane);    // a3 = lv0.p2
    if (lane == 0) CB[7] = p;
    p = lds_dot300(lv0S, tgt + 11 * TGT_P, lane);         // qv2
    if (lane == 0) CB[10] = p;
  } else if (wave == 6) {
    float p = lds_dot300(lv0S, tgt + 9 * TGT_P, lane);    // qv0
    if (lane == 0) CB[8] = p;
  } else if (wave == 7) {
    float p = lds_dot300(lv0S, tgt + 10 * TGT_P, lane);   // qv1
    if (lane == 0) CB[9] = p;
  }
  __syncthreads();

  const float ab = attn_b[0];
  float sdot = CB[0] + ab;

#pragma unroll
  for (int h = 0; h < 3; ++h) {
    float s = (tid < cl) ? tanhf(m_l + sdot) : -1e9f;
    float mx = s;
#pragma unroll
    for (int off = 32; off; off >>= 1) mx = fmaxf(mx, __shfl_down(mx, off, 64));
    if (lane == 0) sred[wave][0] = mx;
    __syncthreads();
    if (tid == 0) {
      float mm = sred[0][0];
      for (int w = 1; w < 8; ++w) mm = fmaxf(mm, sred[w][0]);
      XB[0] = mm;
    }
    __syncthreads();
    float e = expf(s - XB[0]);                 // masked rows -> exactly 0
    float sm = e;
#pragma unroll
    for (int off = 32; off; off >>= 1) sm += __shfl_down(sm, off, 64);
    if (lane == 0) sred[wave][0] = sm;
    __syncthreads();
    if (tid == 0) {
      float ss = 0.f;
      for (int w = 0; w < 8; ++w) ss += sred[w][0];
      XB[1] = 1.0f / ss;
    }
    __syncthreads();
    const float alpha = e * XB[1];

    if (h == 0) {
      float v[5] = {alpha*f1, alpha*f2, alpha*g2c0, alpha*g2c1, alpha*g2c2};
      breduceN<5>(v, sred, RB + 0, wave, lane, tid);
      sdot = RB[0] + CB[1] + CB[2] + ab;
    } else if (h == 1) {
      float v[4] = {alpha*f1, alpha*g1c0, alpha*g1c1, alpha*g1c2};
      breduceN<4>(v, sred, RB + 5, wave, lane, tid);
      sdot = RB[5] + RB[1] + CB[7] + CB[3] + CB[2] + ab;
    } else {
      float v[3] = {alpha*g0c0, alpha*g0c1, alpha*g0c2};
      breduceN<3>(v, sred, RB + 9, wave, lane, tid);
    }
  }

  if (tid < Cc)
    out[b * Cc + tid] = RB[9 + tid] + RB[6 + tid] + RB[2 + tid] +
                        CB[8 + tid] + CB[4 + tid];
}

extern "C" void kernel_launch(void* const* d_in, const int* in_sizes, int n_in,
                              void* d_out, int out_size, void* d_ws, size_t ws_size,
                              hipStream_t stream) {
  const int*   cx     = (const int*)  d_in[0];
  const int*   clen   = (const int*)  d_in[1];
  const int*   tx     = (const int*)  d_in[2];
  const int*   tlen   = (const int*)  d_in[3];
  const int*   tloc   = (const int*)  d_in[4];
  const float* emb    = (const float*)d_in[5];
  const float* attn_w = (const float*)d_in[6];
  const float* attn_b = (const float*)d_in[7];
  const float* lin_w  = (const float*)d_in[8];
  const float* lin_b  = (const float*)d_in[9];
  const float* out_w  = (const float*)d_in[10];
  const float* out_b  = (const float*)d_in[11];
  float* out = (float*)d_out;

  // ws layout (floats): tgt[12][304] | vec0[256*300] | etab[50000*12]  ~2.7 MB
  float* tgt   = (float*)d_ws;
  float* vec0  = tgt  + 12 * TGT_P;
  float* etab  = vec0 + Bc * Dc;

  prep1_kernel<<<557, 256, 0, stream>>>(lin_w, attn_w, out_w, tx, tlen, emb,
                                        tgt, vec0);
  prep2_kernel<<<225, 256, 0, stream>>>(lin_w, tgt);
  etab_kernel<<<1024, 256, 0, stream>>>(emb, tgt, etab);
  hops_kernel<<<Bc, 512, 0, stream>>>(cx, clen, tloc, etab, tgt, vec0,
                                      lin_w, lin_b, attn_b, out_b, out);
}